// Round 1
// 70.369 us; speedup vs baseline: 1.0248x; 1.0248x over previous
//
#include <hip/hip_runtime.h>

#define NB  256   // 2^(6+2) blades
#define NM  127   // even-grade motor components (minus pseudoscalar)
#define NP  8     // grade-1 blades
#define ND  6

// ---------------- compile-time table generation ----------------
// Key algebraic fact exploited here: motor M is even-grade, point P is grade-1
// (odd), so mx = M*P is PURELY ODD-GRADE (128 of 256 positions). The first GP
// only computes odd positions; the second GP indexes mx by odd-ordinal.

constexpr int popc8(int x) { int c = 0; while (x) { c += x & 1; x >>= 1; } return c; }

constexpr int sign_of(int a, int b) {
    int s = 1;
    int aa = a >> 1, cnt = 0;
    while (aa) { cnt += popc8(aa & b); aa >>= 1; }
    if (cnt & 1) s = -s;
    int common = a & b, i = 0;
    while (common) {
        if ((common & 1) && i == 7) s = -s;   // metric[7] = -1
        common >>= 1; ++i;
    }
    return s;
}

struct Tables {
    // first GP, odd outputs only: [odd ordinal oi][k] -> (motor_slot<<1)|neg.
    // motor_slot 127 = zero pad (pseudoscalar position, excluded from motor).
    alignas(16) int firstT[128 * 8];
    // second GP, lane-major: lane l owns output r=l&7 and slots j=(l>>3)+8*m,
    // m=0..15. entry -> (odd_ordinal<<1)|neg, with reverse-sign rev(j) folded
    // into neg. j==127 pad points at ordinal 0 (multiplied by m_s[127]==0).
    alignas(16) int secondT[64 * 16];
};

constexpr Tables build_tables() {
    Tables T{};
    int masks[NB] = {}, pos[NB] = {};
    int t = 0;
    for (int pc = 0; pc <= 8; ++pc)
        for (int m = 0; m < NB; ++m)
            if (popc8(m) == pc) masks[t++] = m;
    for (int i = 0; i < NB; ++i) pos[masks[i]] = i;

    // odd-grade ordinals (ascending position order)
    int oi_of[NB] = {}; int odd_pos[128] = {}; int no = 0;
    for (int i = 0; i < NB; ++i) oi_of[i] = -1;
    for (int i = 0; i < NB; ++i)
        if (popc8(masks[i]) & 1) { odd_pos[no] = i; oi_of[i] = no; ++no; }

    // motor slots: even grade, mask != 255, ascending position
    int invm[NB] = {}; int mpos[NM] = {}; int rev[NM] = {};
    for (int i = 0; i < NB; ++i) invm[i] = -1;
    int j = 0;
    for (int i = 0; i < NB; ++i) {
        int g = popc8(masks[i]);
        if ((g % 2 == 0) && masks[i] != 255) {
            invm[i] = j; mpos[j] = i;
            rev[j] = ((g * (g - 1) / 2) % 2) ? -1 : 1;
            ++j;
        }
    }

    // first GP: mx[odd i] = sum_k sign * motor_slot[m] * point[k]
    for (int o = 0; o < 128; ++o) {
        int i = odd_pos[o];
        for (int k = 0; k < NP; ++k) {
            int pp = 1 + k;                       // grade-1 position
            int m  = pos[masks[i] ^ masks[pp]];   // even-grade (or pseudoscalar)
            int slot = (invm[m] >= 0) ? invm[m] : 127;  // pseudo -> zero pad
            int s  = sign_of(masks[m], masks[pp]);
            T.firstT[o * 8 + k] = (slot << 1) | (s < 0 ? 1 : 0);
        }
    }

    // second GP, lane-major with rev folded in
    for (int l = 0; l < 64; ++l) {
        int r = l & 7, jb = l >> 3;
        int rr = (r < 6) ? r : 0;                 // classes 6,7: dummy (discarded)
        for (int m = 0; m < 16; ++m) {
            int jj = jb + 8 * m;
            if (jj >= NM) { T.secondT[l * 16 + m] = 0; continue; }  // j=127 pad
            int pj = mpos[jj];
            int ii = pos[masks[1 + rr] ^ masks[pj]];   // odd-grade always
            int s  = sign_of(masks[ii], masks[pj]) * rev[jj];
            T.secondT[l * 16 + m] = (oi_of[ii] << 1) | (s < 0 ? 1 : 0);
        }
    }
    return T;
}

constexpr Tables hT = build_tables();
__device__ const Tables dT = hT;   // 8 KB constant-initialized .rodata

// ---------------- wave-per-row kernel: 4 rows per 256-thread block ----------
__global__ __launch_bounds__(256) void cga_apply(
    const float* __restrict__ motor,
    const float* __restrict__ x,
    float*       __restrict__ out)
{
    __shared__ float m_s[4][128];   // per-wave motor by slot (+ zero pad at 127)
    __shared__ float mxs[4][128];   // per-wave odd-grade mx by ordinal

    const int t = threadIdx.x;
    const int w = t >> 6;           // wave id = row within block
    const int l = t & 63;
    const int row = __builtin_amdgcn_readfirstlane((int)(blockIdx.x * 4 + w));

    // coalesced slot-order motor staging (no invm gather)
    const float* mrow = motor + row * NM;
    m_s[w][l]      = mrow[l];
    m_s[w][l + 64] = (l < 63) ? mrow[l + 64] : 0.0f;   // slot 127 = 0 pad

    // point multivector — wave-uniform (row uniform -> scalar loads possible)
    const float* xr = x + row * ND;
    float pv[NP];
    float h = 0.0f;
    #pragma unroll
    for (int k = 0; k < ND; ++k) { float v = xr[k]; pv[k] = v; h += v * v; }
    h *= 0.5f;
    pv[6] = h - 0.5f;
    pv[7] = h + 0.5f;

    // per-lane table loads, all contiguous int4 (L1/L2-resident)
    const int4* ft = (const int4*)dT.firstT;
    int4 a0 = ft[2 * l],        a1 = ft[2 * l + 1];
    int4 b0 = ft[2 * (l + 64)], b1 = ft[2 * (l + 64) + 1];
    const int4* st = (const int4*)dT.secondT;
    int4 c0 = st[4 * l], c1 = st[4 * l + 1], c2 = st[4 * l + 2], c3 = st[4 * l + 3];

    __syncthreads();

    // ---- first GP (odd positions only): lane computes ordinals l and l+64
    int fa[8] = {a0.x, a0.y, a0.z, a0.w, a1.x, a1.y, a1.z, a1.w};
    int fb[8] = {b0.x, b0.y, b0.z, b0.w, b1.x, b1.y, b1.z, b1.w};
    float acc0 = 0.0f, acc1 = 0.0f;
    #pragma unroll
    for (int k = 0; k < NP; ++k) {
        float v = m_s[w][fa[k] >> 1] * pv[k];
        acc0 += (fa[k] & 1) ? -v : v;
    }
    #pragma unroll
    for (int k = 0; k < NP; ++k) {
        float v = m_s[w][fb[k] >> 1] * pv[k];
        acc1 += (fb[k] & 1) ? -v : v;
    }
    mxs[w][l]      = acc0;
    mxs[w][l + 64] = acc1;

    __syncthreads();

    // ---- second GP: lane l owns output r=l&7, slots j=(l>>3)+8m
    const int jb = l >> 3;
    int se[16] = {c0.x, c0.y, c0.z, c0.w, c1.x, c1.y, c1.z, c1.w,
                  c2.x, c2.y, c2.z, c2.w, c3.x, c3.y, c3.z, c3.w};
    float o = 0.0f;
    #pragma unroll
    for (int m = 0; m < 16; ++m) {
        int e = se[m];
        float v = mxs[w][e >> 1] * m_s[w][jb + 8 * m];  // rev sign folded in e
        o += (e & 1) ? -v : v;
    }

    // mod-8 class reduction: 3 shuffles instead of 36; lanes 0..5 hold out[0..5]
    o += __shfl_xor(o, 8, 64);
    o += __shfl_xor(o, 16, 64);
    o += __shfl_xor(o, 32, 64);

    if (l < ND) out[row * ND + l] = o;   // 24B coalesced store per wave
}

extern "C" void kernel_launch(void* const* d_in, const int* in_sizes, int n_in,
                              void* d_out, int out_size, void* d_ws, size_t ws_size,
                              hipStream_t stream) {
    const float* motor = (const float*)d_in[0];
    const float* x     = (const float*)d_in[1];
    // d_in[2..8] (tables/masks) are deterministic — baked in at compile time.
    float* out = (float*)d_out;

    const int Bsz = in_sizes[0] / NM;   // 1024
    cga_apply<<<Bsz / 4, 256, 0, stream>>>(motor, x, out);
}